// Round 10
// baseline (411.085 us; speedup 1.0000x reference)
//
#include <hip/hip_runtime.h>

#define NN 100000
#define NE 3200000
#define DD 64

constexpr int ELEMS = NN * DD;            // 6,400,000
constexpr int NBK   = (NN + 255) / 256;   // 391 buckets of 256 nodes
constexpr int NBLK  = 512;                // partition blocks
constexpr int EPB   = NE / NBLK;          // 6250 edges per block (exact)

// ---------------- Threefry-2x32, key = (0, 42), 20 rounds ----------------
__device__ __forceinline__ void threefry2x32_0_42(unsigned int c0, unsigned int c1,
                                                  unsigned int& o0, unsigned int& o1) {
  const unsigned int ks0 = 0u;
  const unsigned int ks1 = 42u;
  const unsigned int ks2 = ks0 ^ ks1 ^ 0x1BD11BDAu;
  unsigned int x0 = c0 + ks0;
  unsigned int x1 = c1 + ks1;
#define TF_R(r) { x0 += x1; x1 = (x1 << (r)) | (x1 >> (32 - (r))); x1 ^= x0; }
  TF_R(13) TF_R(15) TF_R(26) TF_R(6)
  x0 += ks1; x1 += ks2 + 1u;
  TF_R(17) TF_R(29) TF_R(16) TF_R(24)
  x0 += ks2; x1 += ks0 + 2u;
  TF_R(13) TF_R(15) TF_R(26) TF_R(6)
  x0 += ks0; x1 += ks1 + 3u;
  TF_R(17) TF_R(29) TF_R(16) TF_R(24)
  x0 += ks1; x1 += ks2 + 4u;
  TF_R(13) TF_R(15) TF_R(26) TF_R(6)
  x0 += ks2; x1 += ks0 + 5u;
#undef TF_R
  o0 = x0; o1 = x1;
}

__device__ __forceinline__ bool keep_from_bits(unsigned int bits) {
  float f = __uint_as_float((bits >> 9) | 0x3f800000u) - 1.0f;
  return f < 0.9f;
}

// ---------------- fused: partition pass 1 (blocks 0..NBLK-1) + tanh/sign (rest) ----------------
__global__ void k_init(const float* __restrict__ x,
                       float* __restrict__ h_out,
                       float* __restrict__ h0f,
                       const int* __restrict__ dst,
                       int* __restrict__ counts) {
  __shared__ int c[NBK];
  if (blockIdx.x < NBLK) {
    int blk = blockIdx.x, t = threadIdx.x;
    for (int i = t; i < NBK; i += blockDim.x) c[i] = 0;
    __syncthreads();
    int e0 = blk * EPB;
    for (int e = e0 + t; e < e0 + EPB; e += blockDim.x)
      atomicAdd(&c[dst[e] >> 8], 1);
    __syncthreads();
    for (int i = t; i < NBK; i += blockDim.x) counts[i * NBLK + blk] = c[i];
  } else {
    int i = (blockIdx.x - NBLK) * blockDim.x + threadIdx.x;
    if (i >= ELEMS) return;
    float xv = x[i];
    h0f[i] = (float)tanh((double)xv);
    h_out[i] = (xv > 0.0f) ? 1.0f : ((xv < 0.0f) ? -1.0f : 0.0f);
  }
}

// ---------------- partition pass 2: per-bucket exclusive scan over blocks + totals ----------------
__global__ void k_bofs(const int* __restrict__ counts,
                       int* __restrict__ offs_local, int* __restrict__ btot) {
  __shared__ int s[NBLK];
  int b = blockIdx.x, t = threadIdx.x;
  int own = counts[b * NBLK + t];
  s[t] = own;
  __syncthreads();
  for (int off = 1; off < NBLK; off <<= 1) {
    int add = (t >= off) ? s[t - off] : 0;
    __syncthreads();
    s[t] += add;
    __syncthreads();
  }
  offs_local[b * NBLK + t] = s[t] - own;
  if (t == NBLK - 1) btot[b] = s[t];
}

// ---------------- bucket bases: exclusive scan of 391 totals ----------------
__global__ void k_bbase(const int* __restrict__ btot, int* __restrict__ bbase) {
  __shared__ int s[NBLK];
  int t = threadIdx.x;
  int own = (t < NBK) ? btot[t] : 0;
  s[t] = own;
  __syncthreads();
  for (int off = 1; off < NBLK; off <<= 1) {
    int add = (t >= off) ? s[t - off] : 0;
    __syncthreads();
    s[t] += add;
    __syncthreads();
  }
  if (t < NBK) bbase[t] = s[t] - own;
  if (t == 0) bbase[NBK] = NE;
}

// ---------------- partition pass 3: LDS counting sort + segment-contiguous write ----------------
__global__ void __launch_bounds__(512) k_bwrite(const int* __restrict__ src,
                                                const int* __restrict__ dst,
                                                const int* __restrict__ offs_local,
                                                const int* __restrict__ bbase,
                                                unsigned int* __restrict__ ebuf) {
  __shared__ unsigned int stage[EPB];
  __shared__ unsigned short bstage[EPB];
  __shared__ int cnt[NBK];
  __shared__ int sc[NBLK];
  __shared__ int cur[NBK];
  __shared__ int obase[NBK];
  int blk = blockIdx.x, t = threadIdx.x;
  int e0 = blk * EPB;

  for (int i = t; i < NBK; i += blockDim.x) cnt[i] = 0;
  __syncthreads();
  for (int e = e0 + t; e < e0 + EPB; e += blockDim.x)
    atomicAdd(&cnt[dst[e] >> 8], 1);
  __syncthreads();
  int own = (t < NBK) ? cnt[t] : 0;
  sc[t] = own;
  __syncthreads();
  for (int off = 1; off < NBLK; off <<= 1) {
    int add = (t >= off) ? sc[t - off] : 0;
    __syncthreads();
    sc[t] += add;
    __syncthreads();
  }
  if (t < NBK) {
    cur[t] = sc[t] - own;
    obase[t] = bbase[t] + offs_local[t * NBLK + blk];
  }
  __syncthreads();
  for (int e = e0 + t; e < e0 + EPB; e += blockDim.x) {
    int d = dst[e];
    int b = d >> 8;
    int p = atomicAdd(&cur[b], 1);
    stage[p] = ((unsigned int)src[e] << 8) | (unsigned int)(d & 255);
    bstage[p] = (unsigned short)b;
  }
  __syncthreads();
  for (int i = t; i < EPB; i += blockDim.x) {
    int b = (int)bstage[i];
    int local_excl = sc[b] - cnt[b];
    ebuf[obase[b] + (i - local_excl)] = stage[i];
  }
}

// ---------------- fused: per-bucket node histogram -> rowptr + csr fill ----------------
__global__ void k_fill(const int* __restrict__ bbase, const unsigned int* __restrict__ ebuf,
                       int* __restrict__ rowptr, int* __restrict__ csr_src) {
  __shared__ int cnt[256];
  __shared__ int sc[256];
  __shared__ int cur[256];
  int b = blockIdx.x;
  int t = threadIdx.x;
  int seg_beg = bbase[b];
  int seg_end = bbase[b + 1];
  int nfirst = b << 8;
  int ncount = min(256, NN - nfirst);

  cnt[t] = 0;
  __syncthreads();
  for (int j = seg_beg + t; j < seg_end; j += 256)
    atomicAdd(&cnt[ebuf[j] & 255u], 1);
  __syncthreads();
  int own = cnt[t];
  sc[t] = own;
  __syncthreads();
  for (int off = 1; off < 256; off <<= 1) {
    int add = (t >= off) ? sc[t - off] : 0;
    __syncthreads();
    sc[t] += add;
    __syncthreads();
  }
  if (t < ncount) {
    rowptr[nfirst + t + 1] = seg_beg + sc[t];
    cur[t] = seg_beg + sc[t] - own;
  }
  if (b == 0 && t == 0) rowptr[0] = 0;
  __syncthreads();
  for (int j = seg_beg + t; j < seg_end; j += 256) {
    unsigned int v = ebuf[j];
    int pos = atomicAdd(&cur[v & 255u], 1);
    csr_src[pos] = (int)(v >> 8);
  }
}

// ---------------- G1: per-node gather, exact f64 accumulate -> sign bit-planes ----------------
// one 64-lane wave per node; lane = feature. pos/neg planes via wave ballot.
__global__ void k_gather1(const int* __restrict__ rowptr, const int* __restrict__ csr_src,
                          const float* __restrict__ h0f, ulonglong2* __restrict__ pp) {
  int g = blockIdx.x * blockDim.x + threadIdx.x;
  int n = g >> 6;
  int lane = g & 63;
  if (n >= NN) return;
  int beg = rowptr[n], end = rowptr[n + 1];
  double acc = (double)h0f[n * DD + lane];  // self-loop
  int j = beg;
  for (; j + 4 <= end; j += 4) {
    int s0 = csr_src[j], s1 = csr_src[j + 1], s2 = csr_src[j + 2], s3 = csr_src[j + 3];
    float v0 = h0f[s0 * DD + lane];
    float v1 = h0f[s1 * DD + lane];
    float v2 = h0f[s2 * DD + lane];
    float v3 = h0f[s3 * DD + lane];
    acc += (double)v0; acc += (double)v1; acc += (double)v2; acc += (double)v3;
  }
  for (; j < end; ++j) acc += (double)h0f[csr_src[j] * DD + lane];
  unsigned long long bp = __ballot(acc > 0.0);
  unsigned long long bn = __ballot(acc < 0.0);
  if (lane == 0) {
    ulonglong2 v; v.x = bp; v.y = bn;
    pp[n] = v;
  }
}

// ---------------- G2: bit-plane gather + sign + partitionable-threefry dropout ----------------
// per edge: ONE uniform 16B load (pos,neg planes); lane extracts its feature bit.
__global__ void k_gather2(const int* __restrict__ rowptr, const int* __restrict__ csr_src,
                          const ulonglong2* __restrict__ pp, float* __restrict__ out2) {
  int g = blockIdx.x * blockDim.x + threadIdx.x;
  int n = g >> 6;
  int lane = g & 63;
  if (n >= NN) return;
  int beg = rowptr[n], end = rowptr[n + 1];
  ulonglong2 ps = pp[n];  // self-loop
  int acc = (int)((ps.x >> lane) & 1ull) - (int)((ps.y >> lane) & 1ull);
  int j = beg;
  for (; j + 4 <= end; j += 4) {
    int s0 = csr_src[j], s1 = csr_src[j + 1], s2 = csr_src[j + 2], s3 = csr_src[j + 3];
    ulonglong2 p0 = pp[s0];
    ulonglong2 p1 = pp[s1];
    ulonglong2 p2 = pp[s2];
    ulonglong2 p3 = pp[s3];
    acc += (int)((p0.x >> lane) & 1ull) - (int)((p0.y >> lane) & 1ull);
    acc += (int)((p1.x >> lane) & 1ull) - (int)((p1.y >> lane) & 1ull);
    acc += (int)((p2.x >> lane) & 1ull) - (int)((p2.y >> lane) & 1ull);
    acc += (int)((p3.x >> lane) & 1ull) - (int)((p3.y >> lane) & 1ull);
  }
  for (; j < end; ++j) {
    ulonglong2 p = pp[csr_src[j]];
    acc += (int)((p.x >> lane) & 1ull) - (int)((p.y >> lane) & 1ull);
  }

  int i = n * DD + lane;
  float s = (acc > 0) ? 1.0f : ((acc < 0) ? -1.0f : 0.0f);
  unsigned int o0, o1;
  threefry2x32_0_42(0u, (unsigned int)i, o0, o1);
  unsigned int bits = o0 ^ o1;
  const float inv_keep = 1.0f / 0.9f;
  out2[i] = keep_from_bits(bits) ? s * inv_keep : 0.0f;
}

extern "C" void kernel_launch(void* const* d_in, const int* in_sizes, int n_in,
                              void* d_out, int out_size, void* d_ws, size_t ws_size,
                              hipStream_t stream) {
  const float* x   = (const float*)d_in[0];
  const int*   ei  = (const int*)d_in[1];
  const int*   src = ei;        // edge_index[0]
  const int*   dst = ei + NE;   // edge_index[1]

  float* out_h  = (float*)d_out;           // output 0: h    [ELEMS]
  float* out_h2 = (float*)d_out + ELEMS;   // output 1: h_2  [ELEMS]

  char* ws = (char*)d_ws;
  float*        h0f        = (float*)ws;                               // 25.6 MB @ 0
  ulonglong2*   pp         = (ulonglong2*)(ws + ((size_t)26 << 20));   // 1.6 MB
  int*          rowptr     = (int*)(ws + ((size_t)28 << 20));          // 400 KB + 4
  int*          bbase      = (int*)(ws + ((size_t)29 << 20));          // 1.6 KB
  int*          btot       = (int*)(ws + ((size_t)30 << 20));          // 1.6 KB
  int*          counts     = (int*)(ws + ((size_t)31 << 20));          // 800 KB
  int*          offs_local = (int*)(ws + ((size_t)32 << 20));          // 800 KB
  int*          csr_src    = (int*)(ws + ((size_t)33 << 20));          // 12.8 MB
  unsigned int* ebuf       = (unsigned int*)(ws + ((size_t)46 << 20)); // 12.8 MB

  const int B = 256;
  const int gElems = (ELEMS + B - 1) / B;          // 25000

  k_init<<<NBLK + gElems, B, 0, stream>>>(x, out_h, h0f, dst, counts);
  k_bofs<<<NBK, NBLK, 0, stream>>>(counts, offs_local, btot);
  k_bbase<<<1, NBLK, 0, stream>>>(btot, bbase);
  k_bwrite<<<NBLK, NBLK, 0, stream>>>(src, dst, offs_local, bbase, ebuf);
  k_fill<<<NBK, B, 0, stream>>>(bbase, ebuf, rowptr, csr_src);

  k_gather1<<<gElems, B, 0, stream>>>(rowptr, csr_src, h0f, pp);
  k_gather2<<<gElems, B, 0, stream>>>(rowptr, csr_src, pp, out_h2);
}

// Round 11
// 363.525 us; speedup vs baseline: 1.1308x; 1.1308x over previous
//
#include <hip/hip_runtime.h>

#define NN 100000
#define NE 3200000
#define DD 64

constexpr int ELEMS = NN * DD;            // 6,400,000
constexpr int NBK   = (NN + 255) / 256;   // 391 buckets of 256 nodes
constexpr int NBLK  = 512;                // partition blocks
constexpr int EPB   = NE / NBLK;          // 6250 edges per block (exact)

// ---------------- Threefry-2x32, key = (0, 42), 20 rounds ----------------
__device__ __forceinline__ void threefry2x32_0_42(unsigned int c0, unsigned int c1,
                                                  unsigned int& o0, unsigned int& o1) {
  const unsigned int ks0 = 0u;
  const unsigned int ks1 = 42u;
  const unsigned int ks2 = ks0 ^ ks1 ^ 0x1BD11BDAu;
  unsigned int x0 = c0 + ks0;
  unsigned int x1 = c1 + ks1;
#define TF_R(r) { x0 += x1; x1 = (x1 << (r)) | (x1 >> (32 - (r))); x1 ^= x0; }
  TF_R(13) TF_R(15) TF_R(26) TF_R(6)
  x0 += ks1; x1 += ks2 + 1u;
  TF_R(17) TF_R(29) TF_R(16) TF_R(24)
  x0 += ks2; x1 += ks0 + 2u;
  TF_R(13) TF_R(15) TF_R(26) TF_R(6)
  x0 += ks0; x1 += ks1 + 3u;
  TF_R(17) TF_R(29) TF_R(16) TF_R(24)
  x0 += ks1; x1 += ks2 + 4u;
  TF_R(13) TF_R(15) TF_R(26) TF_R(6)
  x0 += ks2; x1 += ks0 + 5u;
#undef TF_R
  o0 = x0; o1 = x1;
}

__device__ __forceinline__ bool keep_from_bits(unsigned int bits) {
  float f = __uint_as_float((bits >> 9) | 0x3f800000u) - 1.0f;
  return f < 0.9f;
}

// ---------------- fused: partition pass 1 (blocks 0..NBLK-1) + tanh/sign (rest) ----------------
__global__ void k_init(const float* __restrict__ x,
                       float* __restrict__ h_out,
                       float* __restrict__ h0f,
                       const int* __restrict__ dst,
                       int* __restrict__ counts) {
  __shared__ int c[NBK];
  if (blockIdx.x < NBLK) {
    int blk = blockIdx.x, t = threadIdx.x;
    for (int i = t; i < NBK; i += blockDim.x) c[i] = 0;
    __syncthreads();
    int e0 = blk * EPB;
    for (int e = e0 + t; e < e0 + EPB; e += blockDim.x)
      atomicAdd(&c[dst[e] >> 8], 1);
    __syncthreads();
    for (int i = t; i < NBK; i += blockDim.x) counts[i * NBLK + blk] = c[i];
  } else {
    int i = (blockIdx.x - NBLK) * blockDim.x + threadIdx.x;
    if (i >= ELEMS) return;
    float xv = x[i];
    h0f[i] = (float)tanh((double)xv);
    h_out[i] = (xv > 0.0f) ? 1.0f : ((xv < 0.0f) ? -1.0f : 0.0f);
  }
}

// ---------------- partition pass 2: per-bucket exclusive scan over blocks + totals ----------------
__global__ void k_bofs(const int* __restrict__ counts,
                       int* __restrict__ offs_local, int* __restrict__ btot) {
  __shared__ int s[NBLK];
  int b = blockIdx.x, t = threadIdx.x;
  int own = counts[b * NBLK + t];
  s[t] = own;
  __syncthreads();
  for (int off = 1; off < NBLK; off <<= 1) {
    int add = (t >= off) ? s[t - off] : 0;
    __syncthreads();
    s[t] += add;
    __syncthreads();
  }
  offs_local[b * NBLK + t] = s[t] - own;
  if (t == NBLK - 1) btot[b] = s[t];
}

// ---------------- bucket bases: exclusive scan of 391 totals ----------------
__global__ void k_bbase(const int* __restrict__ btot, int* __restrict__ bbase) {
  __shared__ int s[NBLK];
  int t = threadIdx.x;
  int own = (t < NBK) ? btot[t] : 0;
  s[t] = own;
  __syncthreads();
  for (int off = 1; off < NBLK; off <<= 1) {
    int add = (t >= off) ? s[t - off] : 0;
    __syncthreads();
    s[t] += add;
    __syncthreads();
  }
  if (t < NBK) bbase[t] = s[t] - own;
  if (t == 0) bbase[NBK] = NE;
}

// ---------------- partition pass 3: LDS counting sort + segment-contiguous write ----------------
__global__ void __launch_bounds__(512) k_bwrite(const int* __restrict__ src,
                                                const int* __restrict__ dst,
                                                const int* __restrict__ offs_local,
                                                const int* __restrict__ bbase,
                                                unsigned int* __restrict__ ebuf) {
  __shared__ unsigned int stage[EPB];
  __shared__ unsigned short bstage[EPB];
  __shared__ int cnt[NBK];
  __shared__ int sc[NBLK];
  __shared__ int cur[NBK];
  __shared__ int obase[NBK];
  int blk = blockIdx.x, t = threadIdx.x;
  int e0 = blk * EPB;

  for (int i = t; i < NBK; i += blockDim.x) cnt[i] = 0;
  __syncthreads();
  for (int e = e0 + t; e < e0 + EPB; e += blockDim.x)
    atomicAdd(&cnt[dst[e] >> 8], 1);
  __syncthreads();
  int own = (t < NBK) ? cnt[t] : 0;
  sc[t] = own;
  __syncthreads();
  for (int off = 1; off < NBLK; off <<= 1) {
    int add = (t >= off) ? sc[t - off] : 0;
    __syncthreads();
    sc[t] += add;
    __syncthreads();
  }
  if (t < NBK) {
    cur[t] = sc[t] - own;
    obase[t] = bbase[t] + offs_local[t * NBLK + blk];
  }
  __syncthreads();
  for (int e = e0 + t; e < e0 + EPB; e += blockDim.x) {
    int d = dst[e];
    int b = d >> 8;
    int p = atomicAdd(&cur[b], 1);
    stage[p] = ((unsigned int)src[e] << 8) | (unsigned int)(d & 255);
    bstage[p] = (unsigned short)b;
  }
  __syncthreads();
  for (int i = t; i < EPB; i += blockDim.x) {
    int b = (int)bstage[i];
    int local_excl = sc[b] - cnt[b];
    ebuf[obase[b] + (i - local_excl)] = stage[i];
  }
}

// ---------------- fused: per-bucket node histogram -> rowptr + csr fill ----------------
__global__ void k_fill(const int* __restrict__ bbase, const unsigned int* __restrict__ ebuf,
                       int* __restrict__ rowptr, int* __restrict__ csr_src) {
  __shared__ int cnt[256];
  __shared__ int sc[256];
  __shared__ int cur[256];
  int b = blockIdx.x;
  int t = threadIdx.x;
  int seg_beg = bbase[b];
  int seg_end = bbase[b + 1];
  int nfirst = b << 8;
  int ncount = min(256, NN - nfirst);

  cnt[t] = 0;
  __syncthreads();
  for (int j = seg_beg + t; j < seg_end; j += 256)
    atomicAdd(&cnt[ebuf[j] & 255u], 1);
  __syncthreads();
  int own = cnt[t];
  sc[t] = own;
  __syncthreads();
  for (int off = 1; off < 256; off <<= 1) {
    int add = (t >= off) ? sc[t - off] : 0;
    __syncthreads();
    sc[t] += add;
    __syncthreads();
  }
  if (t < ncount) {
    rowptr[nfirst + t + 1] = seg_beg + sc[t];
    cur[t] = seg_beg + sc[t] - own;
  }
  if (b == 0 && t == 0) rowptr[0] = 0;
  __syncthreads();
  for (int j = seg_beg + t; j < seg_end; j += 256) {
    unsigned int v = ebuf[j];
    int pos = atomicAdd(&cur[v & 255u], 1);
    csr_src[pos] = (int)(v >> 8);
  }
}

// ---------------- G1: per-node gather, exact f64 accumulate, sign -> int8 ----------------
// one 64-lane wave per node; lane = feature
__global__ void k_gather1(const int* __restrict__ rowptr, const int* __restrict__ csr_src,
                          const float* __restrict__ h0f, signed char* __restrict__ h1) {
  int g = blockIdx.x * blockDim.x + threadIdx.x;
  int n = g >> 6;
  int lane = g & 63;
  if (n >= NN) return;
  int beg = rowptr[n], end = rowptr[n + 1];
  double acc = (double)h0f[n * DD + lane];  // self-loop
  int j = beg;
  for (; j + 4 <= end; j += 4) {
    int s0 = csr_src[j], s1 = csr_src[j + 1], s2 = csr_src[j + 2], s3 = csr_src[j + 3];
    float v0 = h0f[s0 * DD + lane];
    float v1 = h0f[s1 * DD + lane];
    float v2 = h0f[s2 * DD + lane];
    float v3 = h0f[s3 * DD + lane];
    acc += (double)v0; acc += (double)v1; acc += (double)v2; acc += (double)v3;
  }
  for (; j < end; ++j) acc += (double)h0f[csr_src[j] * DD + lane];
  h1[n * DD + lane] = (acc > 0.0) ? 1 : ((acc < 0.0) ? -1 : 0);
}

// ---------------- G2: per-node int8 gather + sign + partitionable-threefry dropout ----------------
__global__ void k_gather2(const int* __restrict__ rowptr, const int* __restrict__ csr_src,
                          const signed char* __restrict__ h1, float* __restrict__ out2) {
  int g = blockIdx.x * blockDim.x + threadIdx.x;
  int n = g >> 6;
  int lane = g & 63;
  if (n >= NN) return;
  int beg = rowptr[n], end = rowptr[n + 1];
  int acc = (int)h1[n * DD + lane];  // self-loop
  int j = beg;
  for (; j + 4 <= end; j += 4) {
    int s0 = csr_src[j], s1 = csr_src[j + 1], s2 = csr_src[j + 2], s3 = csr_src[j + 3];
    acc += (int)h1[s0 * DD + lane] + (int)h1[s1 * DD + lane]
         + (int)h1[s2 * DD + lane] + (int)h1[s3 * DD + lane];
  }
  for (; j < end; ++j) acc += (int)h1[csr_src[j] * DD + lane];

  int i = n * DD + lane;
  float s = (acc > 0) ? 1.0f : ((acc < 0) ? -1.0f : 0.0f);
  unsigned int o0, o1;
  threefry2x32_0_42(0u, (unsigned int)i, o0, o1);
  unsigned int bits = o0 ^ o1;
  const float inv_keep = 1.0f / 0.9f;
  out2[i] = keep_from_bits(bits) ? s * inv_keep : 0.0f;
}

extern "C" void kernel_launch(void* const* d_in, const int* in_sizes, int n_in,
                              void* d_out, int out_size, void* d_ws, size_t ws_size,
                              hipStream_t stream) {
  const float* x   = (const float*)d_in[0];
  const int*   ei  = (const int*)d_in[1];
  const int*   src = ei;        // edge_index[0]
  const int*   dst = ei + NE;   // edge_index[1]

  float* out_h  = (float*)d_out;           // output 0: h    [ELEMS]
  float* out_h2 = (float*)d_out + ELEMS;   // output 1: h_2  [ELEMS]

  char* ws = (char*)d_ws;
  float*        h0f        = (float*)ws;                               // 25.6 MB @ 0
  signed char*  h1         = (signed char*)(ws + ((size_t)26 << 20));  // 6.4 MB
  int*          rowptr     = (int*)(ws + ((size_t)33 << 20));          // 400 KB + 4
  int*          bbase      = (int*)(ws + ((size_t)34 << 20));          // 1.6 KB
  int*          btot       = (int*)(ws + ((size_t)35 << 20));          // 1.6 KB
  int*          counts     = (int*)(ws + ((size_t)36 << 20));          // 800 KB
  int*          offs_local = (int*)(ws + ((size_t)37 << 20));          // 800 KB
  int*          csr_src    = (int*)(ws + ((size_t)38 << 20));          // 12.8 MB
  unsigned int* ebuf       = (unsigned int*)(ws + ((size_t)51 << 20)); // 12.8 MB

  const int B = 256;
  const int gElems = (ELEMS + B - 1) / B;          // 25000

  k_init<<<NBLK + gElems, B, 0, stream>>>(x, out_h, h0f, dst, counts);
  k_bofs<<<NBK, NBLK, 0, stream>>>(counts, offs_local, btot);
  k_bbase<<<1, NBLK, 0, stream>>>(btot, bbase);
  k_bwrite<<<NBLK, NBLK, 0, stream>>>(src, dst, offs_local, bbase, ebuf);
  k_fill<<<NBK, B, 0, stream>>>(bbase, ebuf, rowptr, csr_src);

  k_gather1<<<gElems, B, 0, stream>>>(rowptr, csr_src, h0f, h1);
  k_gather2<<<gElems, B, 0, stream>>>(rowptr, csr_src, h1, out_h2);
}